// Round 8
// baseline (293.330 us; speedup 1.0000x reference)
//
#include <hip/hip_runtime.h>
#include <hip/hip_bf16.h>
#include <stdint.h>

// Problem constants: B=8, S=2048, D_IN=4096, D_OUT=4096
#define MROWS 16384
#define DIN   4096
#define DOUT  4096
#define KEFF  1024

typedef __attribute__((ext_vector_type(8)))  __bf16 bf16x8;
typedef __attribute__((ext_vector_type(16))) float  f32x16;

#define AS1 __attribute__((address_space(1)))
#define AS3 __attribute__((address_space(3)))

__device__ __forceinline__ uint32_t f2bf_rne(float f) {
  union { float f; uint32_t u; } v; v.f = f;
  uint32_t u = v.u;
  return (u + 0x7fffu + ((u >> 16) & 1u)) >> 16;
}

// Merged gather: 2-of-8 (positions 0,2 per group of 8) for x then w.
__global__ void venom_gather_all(const float* __restrict__ x,
                                 const float* __restrict__ w,
                                 uint2* __restrict__ xg, uint2* __restrict__ wg) {
  const int PX = MROWS * (DIN / 16);
  const int PW = DOUT * (DIN / 16);
  int stride = gridDim.x * blockDim.x;
  for (int i = blockIdx.x * blockDim.x + threadIdx.x; i < PX + PW; i += stride) {
    const float* src; uint2* dst; int idx;
    if (i < PX) { src = x; dst = xg; idx = i; }
    else        { src = w; dst = wg; idx = i - PX; }
    const float4* p = reinterpret_cast<const float4*>(src) + (size_t)idx * 4;
    float4 a = p[0];
    float4 b = p[2];
    uint2 r;
    r.x = f2bf_rne(a.x) | (f2bf_rne(a.z) << 16);
    r.y = f2bf_rne(b.x) | (f2bf_rne(b.z) << 16);
    dst[idx] = r;
  }
}

// -------- persistent 256x256 bf16 GEMM, 32x32x16 MFMA, 1-barrier phases ------
// A = Xg [MROWS][KEFF] bf16 row-major, B = Wg [DOUT][KEFF] bf16 row-major (B^T).
// C[m][n] = sum_k A[m][k]*B[n][k] + bias[n], fp32 row-major.
#define BM 256
#define BN 256
#define BK 64
#define NT (KEFF / BK)   // 16
#define TPB 4
#define LTOT (NT * TPB)  // 64

// LDS k-half: [128 superrows][128B]; superrow sr = rows 2sr,2sr+1 (32 k = 64B
// each), 8x16B slots XOR-swizzled by (sr&7).
__device__ __forceinline__ int swz_off(int R, int slot) {
  int sr = R >> 1;
  return sr * 128 + (((((R & 1) << 2) | slot) ^ (sr & 7)) << 4);
}

#define WAIT_VM(n) asm volatile("s_waitcnt vmcnt(" #n ")" ::: "memory")
#define BAR() __builtin_amdgcn_s_barrier()

__global__ __launch_bounds__(512, 2) void venom_gemm_w32(
    const __bf16* __restrict__ A, const __bf16* __restrict__ Bm,
    const float* __restrict__ bias, float* __restrict__ C) {
  // [tile-parity][k-half][16KB] for A and B: 128 KiB
  __shared__ __bf16 As[2][2][128 * 64];
  __shared__ __bf16 Bs[2][2][128 * 64];

  // grid = 256; XCD-bijective swizzle
  int nwg = gridDim.x;
  int cpx = nwg >> 3;
  int bid = blockIdx.x;
  int swz = (bid & 7) * cpx + (bid >> 3);
  int mblk = swz >> 2;
  int ngrp = swz & 3;

  int t = threadIdx.x;
  int wid = t >> 6, l = t & 63;
  int wr = wid >> 2, wc = wid & 3;   // 2x4 wave grid; wave owns 128x64 of C
  int lc = l & 31, hi = l >> 5;      // 32x32 frag: row/col = lane&31, k-group = lane>>5

  const __bf16* Ag = A + (size_t)(mblk * BM) * KEFF;

  float biasr[TPB][2];
  #pragma unroll
  for (int j = 0; j < TPB; ++j)
    #pragma unroll
    for (int tj = 0; tj < 2; ++tj)
      biasr[j][tj] = bias[(ngrp * TPB + j) * BN + wc * 64 + tj * 32 + lc];

  f32x16 acc[4][2] = {};

  // Stage the A (or B) 16KB k-half of global K-iteration L2: 2 loads/thread.
  // Linear LDS dest, inverse-swizzled global source (rule #21).
  auto stageA = [&](int L2, int kh) {
    const int buf = L2 & 1;
    const int k0 = (L2 & (NT - 1)) * BK + kh * 32;
    #pragma unroll
    for (int i = 0; i < 2; ++i) {
      int e = i * 512 + t;
      int sr = e >> 3;
      int s = (e & 7) ^ (sr & 7);
      int row = sr * 2 + (s >> 2);
      int koff = (s & 3) * 8;
      __builtin_amdgcn_global_load_lds(
          (const AS1 uint32_t*)(Ag + (size_t)row * KEFF + k0 + koff),
          ((AS3 uint32_t*)&As[buf][kh][0]) + e * 4, 16, 0, 0);
    }
  };
  auto stageB = [&](int L2, int kh) {
    const int buf = L2 & 1;
    const __bf16* Bg = Bm + (size_t)((ngrp * TPB + (L2 >> 4)) * BN) * KEFF;
    const int k0 = (L2 & (NT - 1)) * BK + kh * 32;
    #pragma unroll
    for (int i = 0; i < 2; ++i) {
      int e = i * 512 + t;
      int sr = e >> 3;
      int s = (e & 7) ^ (sr & 7);
      int row = sr * 2 + (s >> 2);
      int koff = (s & 3) * 8;
      __builtin_amdgcn_global_load_lds(
          (const AS1 uint32_t*)(Bg + (size_t)row * KEFF + k0 + koff),
          ((AS3 uint32_t*)&Bs[buf][kh][0]) + e * 4, 16, 0, 0);
    }
  };

  // Prologue: ring order {A0,B0,A1,B1} of tile 0 (8 loads). Loop gates handle it.
  stageA(0, 0);
  stageB(0, 0);
  stageA(0, 1);
  stageB(0, 1);

  bf16x8 bfr[2][2];   // [nt][ks], persists mh0 -> mh1 within a k-half

  #pragma unroll
  for (int j = 0; j < TPB; ++j) {
    #pragma unroll 1
    for (int kt = 0; kt < NT; ++kt) {
      const int L = j * NT + kt;
      const int cur = kt & 1;
      const bool last = (L == LTOT - 1);

      // Phases (mh,kh): (0,0),(1,0),(0,1),(1,1). One barrier per phase.
      // Gates: ph0 entry vm(4) -> this tile's {A0,B0} landed;
      //        ph2 entry vm(4) -> this tile's {A1,B1} landed (vm(0) on last).
      #pragma unroll
      for (int ph = 0; ph < 4; ++ph) {
        const int mh = ph & 1, kh = ph >> 1;

        if (ph == 0) WAIT_VM(4);
        if (ph == 2) { if (last) WAIT_VM(0); else WAIT_VM(4); }
        BAR();

        // Fragment ds_reads (32x32x16: row = lane&31, k = (lane>>5)*8 within slice)
        const char* aB = (const char*)&As[cur][kh][0];
        bf16x8 af[2][2];
        #pragma unroll
        for (int mt = 0; mt < 2; ++mt)
          #pragma unroll
          for (int ks = 0; ks < 2; ++ks)
            af[mt][ks] = *(const bf16x8*)(aB +
                swz_off(wr * 128 + mh * 64 + mt * 32 + lc, ks * 2 + hi));
        if (mh == 0) {
          const char* bB = (const char*)&Bs[cur][kh][0];
          #pragma unroll
          for (int nt = 0; nt < 2; ++nt)
            #pragma unroll
            for (int ks = 0; ks < 2; ++ks)
              bfr[nt][ks] = *(const bf16x8*)(bB +
                  swz_off(wc * 64 + nt * 32 + lc, ks * 2 + hi));
        }

        // Fine-grained stage: one 16KB half per phase (2 loads), ring {A0,B0,A1,B1}
        if (!last) {
          if (ph == 0) stageA(L + 1, 0);
          else if (ph == 1) stageB(L + 1, 0);
          else if (ph == 2) stageA(L + 1, 1);
          else stageB(L + 1, 1);
        }

        __builtin_amdgcn_s_setprio(1);
        #pragma unroll
        for (int mt = 0; mt < 2; ++mt)
          #pragma unroll
          for (int nt = 0; nt < 2; ++nt) {
            acc[mh * 2 + mt][nt] = __builtin_amdgcn_mfma_f32_32x32x16_bf16(
                af[mt][0], bfr[nt][0], acc[mh * 2 + mt][nt], 0, 0, 0);
            acc[mh * 2 + mt][nt] = __builtin_amdgcn_mfma_f32_32x32x16_bf16(
                af[mt][1], bfr[nt][1], acc[mh * 2 + mt][nt], 0, 0, 0);
          }
        __builtin_amdgcn_s_setprio(0);
      }
    }

    // Epilogue tile j: C/D map col=lane&31, row=(r&3)+8*(r>>2)+4*(lane>>5) [m74/m101]
    {
      int colbase = (ngrp * TPB + j) * BN + wc * 64;
      int rowbase = mblk * BM + wr * 128;
      #pragma unroll
      for (int ti = 0; ti < 4; ++ti)
        #pragma unroll
        for (int tj = 0; tj < 2; ++tj) {
          int col = colbase + tj * 32 + lc;
          float bv = biasr[j][tj];
          f32x16 cv = acc[ti][tj];
          #pragma unroll
          for (int r = 0; r < 16; ++r) {
            int row = rowbase + ti * 32 + (r & 3) + 8 * (r >> 2) + 4 * hi;
            C[(size_t)row * DOUT + col] = cv[r] + bv;
          }
          acc[ti][tj] = (f32x16){};
        }
    }
  }
}

// Fallback
__global__ void venom_naive(const float* __restrict__ x, const float* __restrict__ w,
                            const float* __restrict__ bias, float* __restrict__ out) {
  size_t total = (size_t)MROWS * DOUT;
  size_t stride = (size_t)gridDim.x * blockDim.x;
  for (size_t idx = (size_t)blockIdx.x * blockDim.x + threadIdx.x; idx < total;
       idx += stride) {
    int m = (int)(idx / DOUT), n = (int)(idx % DOUT);
    const float* xr = x + (size_t)m * DIN;
    const float* wr = w + (size_t)n * DIN;
    float s = 0.f;
    for (int g = 0; g < DIN / 8; ++g)
      s += xr[g * 8] * wr[g * 8] + xr[g * 8 + 2] * wr[g * 8 + 2];
    out[idx] = s + bias[n];
  }
}

extern "C" void kernel_launch(void* const* d_in, const int* in_sizes, int n_in,
                              void* d_out, int out_size, void* d_ws, size_t ws_size,
                              hipStream_t stream) {
  const float* x    = (const float*)d_in[0];
  const float* wgt  = (const float*)d_in[1];
  const float* bias = (const float*)d_in[2];
  float* out = (float*)d_out;

  const size_t xg_bytes = (size_t)MROWS * KEFF * 2;
  const size_t wg_bytes = (size_t)DOUT * KEFF * 2;

  if (ws_size < xg_bytes + wg_bytes) {
    venom_naive<<<2048, 256, 0, stream>>>(x, wgt, bias, out);
    return;
  }

  uint32_t* xg = (uint32_t*)d_ws;
  uint32_t* wg = (uint32_t*)((char*)d_ws + xg_bytes);

  venom_gather_all<<<2048, 256, 0, stream>>>(x, wgt, (uint2*)xg, (uint2*)wg);

  venom_gemm_w32<<<(MROWS / BM) * (DOUT / BN / TPB), 512, 0, stream>>>(
      (const __bf16*)xg, (const __bf16*)wg, bias, out);
}